// Round 5
// baseline (310.179 us; speedup 1.0000x reference)
//
#include <hip/hip_runtime.h>
#include <hip/hip_bf16.h>

#define B_ 32
#define S_ 2048
#define D_ 512
#define M_ (B_*S_)   // 65536 rows

typedef __bf16 bf16x8 __attribute__((ext_vector_type(8)));
typedef float  f32x4  __attribute__((ext_vector_type(4)));

__device__ __forceinline__ float tanh_fast(float x){
  float e2 = __expf(2.f * x);                    // inf for large x -> rcp=0 -> 1
  return 1.f - 2.f * __builtin_amdgcn_rcpf(e2 + 1.f);
}

__device__ __forceinline__ bf16x8 cvt8(f32x4 a, f32x4 b){
  bf16x8 t;
  t[0]=(__bf16)a[0]; t[1]=(__bf16)a[1]; t[2]=(__bf16)a[2]; t[3]=(__bf16)a[3];
  t[4]=(__bf16)b[0]; t[5]=(__bf16)b[1]; t[6]=(__bf16)b[2]; t[7]=(__bf16)b[3];
  return t;
}

// ---- reorder w_v (fp32 KxN row-major [e*512+d]) into bf16 MFMA B-frag order ----
// frag f = ks*32 + nt. lane holds B[k = ks*32 + quad*8 + j][n = nt*16 + lm], j=0..7.
__global__ void k_reorder_wv(const float* __restrict__ wv,
                             unsigned short* __restrict__ wvr){
  int frag = blockIdx.x;          // 0..511
  int lane = threadIdx.x;         // 0..63
  int ks = frag >> 5, nt = frag & 31;
  int k0 = ks*32 + (lane>>4)*8;
  int d  = nt*16 + (lane&15);
  bf16x8 t;
  #pragma unroll
  for (int j=0;j<8;++j) t[j] = (__bf16)wv[(k0+j)*D_ + d];
  *reinterpret_cast<uint4*>(wvr + ((size_t)frag*64 + lane)*8) =
      __builtin_bit_cast(uint4, t);
}

// ---- qproj[b,d] = query[b,:] @ w_q[:,d] + bias[d]  (fp32, 4-way K-split) ----
__global__ void k_qproj(const float* __restrict__ q,
                        const float* __restrict__ wq,
                        const float* __restrict__ bias,
                        float* __restrict__ qp){
  int b  = blockIdx.y;
  int t  = threadIdx.x;          // 512
  int dl = t & 127, eg = t >> 7;
  int d  = blockIdx.x*128 + dl;
  __shared__ float qs[D_];
  __shared__ float red[4][128];
  for (int e=t; e<D_; e+=512) qs[e] = q[b*D_+e];
  __syncthreads();
  float acc = 0.f;
  #pragma unroll 8
  for (int i=0;i<128;++i){
    int e = eg*128 + i;
    acc = fmaf(qs[e], wq[(size_t)e*D_+d], acc);
  }
  red[eg][dl] = acc;
  __syncthreads();
  if (eg == 0)
    qp[b*D_+d] = red[0][dl]+red[1][dl]+red[2][dl]+red[3][dl] + bias[d];
}

// ---- fused (value@w_v + qproj + loc) -> tanh -> dot(score_w) -> scores ----
// Block: 64 rows x 512 cols, 4 waves (one per 128-col group, same rows ->
// redundant A issues hit L1). BARRIER-FREE K loop: A loaded per-wave directly
// in frag layout (r2-validated addressing), 1-epoch reg prefetch; B from
// L2-resident wvr. Only one __syncthreads at the score reduction.
__launch_bounds__(256, 2)
__global__ void k_energy(const float* __restrict__ value,
                         const unsigned short* __restrict__ wvr,
                         const float* __restrict__ qp,
                         const float* __restrict__ energy,
                         const float* __restrict__ conv_w,
                         const float* __restrict__ conv_b,
                         const float* __restrict__ score_w,
                         float* __restrict__ scores){
  const int t    = threadIdx.x;
  const int wave = t >> 6;
  const int lane = t & 63;
  const int quad = lane >> 4;
  const int lm   = lane & 15;
  const int row0 = blockIdx.x * 64;
  const int b    = row0 >> 11;          // 64 | 2048 -> one batch per block
  const int s0   = row0 & (S_-1);

  f32x4 acc[4][8];
  #pragma unroll
  for (int mt=0;mt<4;++mt)
    #pragma unroll
    for (int nt=0;nt<8;++nt)
      acc[mt][nt] = (f32x4){0.f,0.f,0.f,0.f};

  // A: lane holds A[m=lm][k=quad*8+j] for row-tile mt (rows row0+mt*16+lm)
  const float* aP = value + (size_t)(row0+lm)*D_ + quad*8;
  // B: frag f = kc*32 + wave*8 + ntl
  const unsigned short* bP = wvr + ((size_t)(wave*8)*64 + lane)*8;

  f32x4 aN[4][2];
  #pragma unroll
  for (int mt=0;mt<4;++mt){
    const float* p = aP + (size_t)mt*16*D_;
    aN[mt][0] = *reinterpret_cast<const f32x4*>(p);
    aN[mt][1] = *reinterpret_cast<const f32x4*>(p+4);
  }

  for (int kc=0; kc<15; ++kc){
    bf16x8 af[4];
    #pragma unroll
    for (int mt=0;mt<4;++mt) af[mt] = cvt8(aN[mt][0], aN[mt][1]);
    #pragma unroll
    for (int mt=0;mt<4;++mt){
      const float* p = aP + (size_t)mt*16*D_ + (kc+1)*32;
      aN[mt][0] = *reinterpret_cast<const f32x4*>(p);
      aN[mt][1] = *reinterpret_cast<const f32x4*>(p+4);
    }
    #pragma unroll
    for (int ntl=0;ntl<8;++ntl){
      bf16x8 bf = __builtin_bit_cast(bf16x8,
        *reinterpret_cast<const uint4*>(bP + (size_t)(kc*32+ntl)*512));
      #pragma unroll
      for (int mt=0;mt<4;++mt)
        acc[mt][ntl] = __builtin_amdgcn_mfma_f32_16x16x32_bf16(af[mt], bf, acc[mt][ntl], 0,0,0);
    }
  }
  { // final kc = 15
    bf16x8 af[4];
    #pragma unroll
    for (int mt=0;mt<4;++mt) af[mt] = cvt8(aN[mt][0], aN[mt][1]);
    #pragma unroll
    for (int ntl=0;ntl<8;++ntl){
      bf16x8 bf = __builtin_bit_cast(bf16x8,
        *reinterpret_cast<const uint4*>(bP + (size_t)(15*32+ntl)*512));
      #pragma unroll
      for (int mt=0;mt<4;++mt)
        acc[mt][ntl] = __builtin_amdgcn_mfma_f32_16x16x32_bf16(af[mt], bf, acc[mt][ntl], 0,0,0);
    }
  }

  // epilogue: per-lane d = wave*128 + ntl*16 + lm
  float sw[8], c0[8], c1[8], c2[8], cb[8], qv[8];
  #pragma unroll
  for (int ntl=0; ntl<8; ++ntl){
    int d = wave*128 + ntl*16 + lm;
    sw[ntl] = score_w[d];
    c0[ntl] = conv_w[d*3+0];
    c1[ntl] = conv_w[d*3+1];
    c2[ntl] = conv_w[d*3+2];
    cb[ntl] = conv_b[d];
    qv[ntl] = qp[b*D_+d];
  }
  __shared__ float red[4][64];
  const float* eB = energy + b*S_;
  #pragma unroll
  for (int mt=0; mt<4; ++mt){
    #pragma unroll
    for (int r=0;r<4;++r){
      int sl = mt*16 + quad*4 + r;              // C/D layout: row=quad*4+reg
      int s  = s0 + sl;
      float em1 = (s > 0)    ? eB[s-1] : 0.f;
      float e0  =              eB[s];
      float ep1 = (s < S_-1) ? eB[s+1] : 0.f;
      float p = 0.f;
      #pragma unroll
      for (int ntl=0; ntl<8; ++ntl){
        float h = acc[mt][ntl][r] + qv[ntl]
                + fmaf(c0[ntl],em1, fmaf(c1[ntl],e0, fmaf(c2[ntl],ep1, cb[ntl])));
        p = fmaf(sw[ntl], tanh_fast(h), p);
      }
      #pragma unroll
      for (int m=1; m<16; m<<=1) p += __shfl_xor(p, m, 64);   // reduce 16 cols
      if (lm == 0) red[wave][sl] = p;
    }
  }
  __syncthreads();
  if (t < 64)
    scores[row0 + t] = red[0][t] + red[1][t] + red[2][t] + red[3][t];
}

// ---- fused softmax + context partial. Block (sc,b): recompute block-wide
// max/sum over scores[b,:] (8 KB, L2-hot; score_b cancels in softmax), write
// align slice to d_out, accumulate 128-s context partial.
__launch_bounds__(512)
__global__ void k_ctx(const float* __restrict__ scores,
                      const float* __restrict__ value,
                      float* __restrict__ out_align,
                      float* __restrict__ cpart){
  int b = blockIdx.y, sc = blockIdx.x;
  int t = threadIdx.x;                 // 512
  int lane = t & 63, wid = t >> 6;     // 8 waves
  __shared__ float redm[8], reds[8];
  __shared__ float als[128];

  float v[4], mx = -3.4e38f;
  #pragma unroll
  for (int i=0;i<4;++i){
    v[i] = scores[b*S_ + t + i*512];
    mx = fmaxf(mx, v[i]);
  }
  #pragma unroll
  for (int m=1;m<64;m<<=1) mx = fmaxf(mx, __shfl_xor(mx, m, 64));
  if (lane==0) redm[wid] = mx;
  __syncthreads();
  #pragma unroll
  for (int w=0;w<8;++w) mx = fmaxf(mx, redm[w]);
  float sum = 0.f;
  #pragma unroll
  for (int i=0;i<4;++i) sum += __expf(v[i]-mx);
  #pragma unroll
  for (int m=1;m<64;m<<=1) sum += __shfl_xor(sum, m, 64);
  if (lane==0) reds[wid] = sum;
  __syncthreads();
  sum = 0.f;
  #pragma unroll
  for (int w=0;w<8;++w) sum += reds[w];
  float inv = 1.f/sum;

  if (t < 128){
    float a = __expf(scores[b*S_ + sc*128 + t] - mx) * inv;
    out_align[b*S_ + sc*128 + t] = a;
    als[t] = a;
  }
  __syncthreads();

  int r = t >> 7;            // 0..3
  int c = (t & 127) * 4;     // 16B per thread
  f32x4 acc = (f32x4){0.f,0.f,0.f,0.f};
  #pragma unroll 8
  for (int i=0;i<32;++i){
    int sl = i*4 + r;
    float al = als[sl];
    f32x4 vv = *reinterpret_cast<const f32x4*>(
                 value + ((size_t)(b*S_ + sc*128 + sl))*D_ + c);
    acc += al * vv;
  }
  __shared__ float lred[4][D_];
  #pragma unroll
  for (int j=0;j<4;++j) lred[r][c+j] = acc[j];
  __syncthreads();
  if (r == 0){
    #pragma unroll
    for (int j=0;j<4;++j)
      cpart[((size_t)(b*16+sc))*D_ + c + j] =
          lred[0][c+j] + lred[1][c+j] + lred[2][c+j] + lred[3][c+j];
  }
}

__global__ void k_ctx_reduce(const float* __restrict__ cpart,
                             float* __restrict__ out_ctx){
  int idx = blockIdx.x*256 + threadIdx.x;   // 0..16383
  int b = idx >> 9, d = idx & 511;
  float s = 0.f;
  #pragma unroll
  for (int j=0;j<16;++j) s += cpart[((size_t)(b*16+j))*D_ + d];
  out_ctx[idx] = s;
}

extern "C" void kernel_launch(void* const* d_in, const int* in_sizes, int n_in,
                              void* d_out, int out_size, void* d_ws, size_t ws_size,
                              hipStream_t stream){
  const float* query   = (const float*)d_in[0];
  const float* value   = (const float*)d_in[1];
  const float* energy  = (const float*)d_in[2];
  const float* conv_w  = (const float*)d_in[3];
  const float* conv_b  = (const float*)d_in[4];
  const float* w_q     = (const float*)d_in[5];
  const float* w_v     = (const float*)d_in[6];
  const float* bias    = (const float*)d_in[7];
  const float* score_w = (const float*)d_in[8];
  // score_b (d_in[9]) cancels in softmax and align/context are its only
  // consumers -> unused.

  char* ws = (char*)d_ws;
  unsigned short* wvr = (unsigned short*)(ws);            // 512 KB (bf16 frags)
  float* qp     = (float*)(ws + (512<<10));               // 64 KB
  float* scores = (float*)(ws + (576<<10));               // 256 KB (65536 f32)
  float* cpart  = (float*)(ws + (832<<10));               // 1 MB (32*16 x 512 f32)
  // total ~1.85 MB

  float* out_ctx   = (float*)d_out;                       // [B, D] fp32
  float* out_align = out_ctx + B_*D_;                     // [B, S] fp32

  k_reorder_wv<<<dim3(512),      dim3(64),  0, stream>>>(w_v, wvr);
  k_qproj     <<<dim3(4,32),     dim3(512), 0, stream>>>(query, w_q, bias, qp);
  k_energy    <<<dim3(M_/64),    dim3(256), 0, stream>>>(value, wvr, qp, energy,
                                                         conv_w, conv_b, score_w, scores);
  k_ctx       <<<dim3(16,B_),    dim3(512), 0, stream>>>(scores, value, out_align, cpart);
  k_ctx_reduce<<<dim3(B_*D_/256),dim3(256), 0, stream>>>(cpart, out_ctx);
}